// Round 1
// baseline (756.366 us; speedup 1.0000x reference)
//
#include <hip/hip_runtime.h>
#include <math.h>

// Problem constants (from reference)
constexpr int DIM  = 1024;   // model dim
constexpr int NB   = 8;      // blocks
constexpr int BDIN = 128;    // dim / NB
constexpr int EMB  = 64;     // per-block qkv emb = NH*HD
constexpr int NH   = 2;
constexpr int HD   = 32;
constexpr int T    = 8;      // tokens per workgroup
constexpr float SCALE = 0.17677669529663687f; // HD^-0.5

// Padded LDS row stride for q/k: 592 = 512+80.
// 592 % 32 == 16 and 592 % 4 == 0  -> score-phase reads are <=4-way
// conflicted and float4-aligned; plain 512 would be a 64-way conflict.
constexpr int QS = 592;
// q/k intra-row index: block n, head h, dim dd  (pad 4 per 32 within block)
__device__ __forceinline__ int qidx(int n, int h, int dd) {
    return n * 72 + h * 36 + dd;
}

__global__ __launch_bounds__(256, 2) void gc_fused(
    const float* __restrict__ x,
    const float* __restrict__ wq,
    const float* __restrict__ wk,
    const float* __restrict__ wv,
    const float* __restrict__ wf,
    float* __restrict__ out)
{
    __shared__ float sq[T][QS];            // q, later reused for attention output
    __shared__ float sk[T][QS];
    __shared__ float sv[T][512];           // v: plain layout (P@V reads are conflict-free)
    __shared__ float sp[T][NH][NB][NB];    // softmax probabilities

    const int tid = threadIdx.x;
    const long tok0 = (long)blockIdx.x * T;

    // ---------------- Phase 1: block-diagonal QKV ----------------
    // 256 threads = 64 columns x 4 waves; each thread: 2 tokens x {q,k,v}.
    {
        const int c  = tid & 63;    // column within block emb (= h*32+dd)
        const int tg = tid >> 6;    // wave id (uniform within wave)
        const int t0 = tg * 2;
        const int h  = c >> 5;
        const int dd = c & 31;

        for (int n = 0; n < NB; ++n) {
            const float* xr0 = x + (tok0 + t0) * DIM + n * BDIN;
            const float* xr1 = xr0 + DIM;
            const float* wqp = wq + n * (BDIN * EMB) + c;
            const float* wkp = wk + n * (BDIN * EMB) + c;
            const float* wvp = wv + n * (BDIN * EMB) + c;
            float aq0 = 0.f, aq1 = 0.f, ak0 = 0.f, ak1 = 0.f, av0 = 0.f, av1 = 0.f;
            #pragma unroll 8
            for (int d = 0; d < BDIN; ++d) {
                const float x0  = xr0[d];                 // wave-uniform address
                const float x1  = xr1[d];
                const float wqv = wqp[(size_t)d * EMB];   // 256B coalesced / wave
                const float wkv = wkp[(size_t)d * EMB];
                const float wvv = wvp[(size_t)d * EMB];
                aq0 = fmaf(x0, wqv, aq0); aq1 = fmaf(x1, wqv, aq1);
                ak0 = fmaf(x0, wkv, ak0); ak1 = fmaf(x1, wkv, ak1);
                av0 = fmaf(x0, wvv, av0); av1 = fmaf(x1, wvv, av1);
            }
            const int qi = qidx(n, h, dd);
            sq[t0][qi]     = aq0 * SCALE;   // fold q-scale here
            sq[t0 + 1][qi] = aq1 * SCALE;
            sk[t0][qi]     = ak0;
            sk[t0 + 1][qi] = ak1;
            sv[t0][n * EMB + c]     = av0;
            sv[t0 + 1][n * EMB + c] = av1;
        }
    }
    __syncthreads();

    // ---------------- Phase 2: scores + softmax ----------------
    // 128 threads: one (token, head, row n) each; row of 8 scores in registers,
    // softmax entirely in-thread (no cross-lane ops).
    if (tid < 128) {
        const int t = tid >> 4;
        const int h = (tid >> 3) & 1;
        const int n = tid & 7;

        float qreg[HD];
        #pragma unroll
        for (int dd = 0; dd < HD; ++dd) qreg[dd] = sq[t][qidx(n, h, dd)];

        float sc[NB];
        #pragma unroll
        for (int m = 0; m < NB; ++m) {
            const float* krow = &sk[t][qidx(m, h, 0)];
            float a = 0.f;
            #pragma unroll
            for (int dd = 0; dd < HD; ++dd) a = fmaf(qreg[dd], krow[dd], a);
            sc[m] = a;
        }
        float mx = sc[0];
        #pragma unroll
        for (int m = 1; m < NB; ++m) mx = fmaxf(mx, sc[m]);
        float sum = 0.f;
        #pragma unroll
        for (int m = 0; m < NB; ++m) { sc[m] = __expf(sc[m] - mx); sum += sc[m]; }
        const float inv = 1.f / sum;
        #pragma unroll
        for (int m = 0; m < NB; ++m) sp[t][h][n][m] = sc[m] * inv;
    }
    __syncthreads();

    // ---------------- Phase 3: out = P @ V  (overwrites sq) ----------------
    // 256 threads = 8 tokens x 32 lanes; dd varies across lanes -> conflict-free
    // sv reads; sp reads are per-wave broadcasts.
    {
        const int t = tid >> 5;
        const int l = tid & 31;
        float o[16];
        #pragma unroll
        for (int r = 0; r < 16; ++r) {
            const int idx = r * 32 + l;        // 0..511
            const int h  = idx >> 8;
            const int n  = (idx >> 5) & 7;
            const int dd = idx & 31;
            float a = 0.f;
            #pragma unroll
            for (int m = 0; m < NB; ++m)
                a = fmaf(sp[t][h][n][m], sv[t][m * EMB + h * HD + dd], a);
            o[r] = a;
        }
        // q is dead after phase 2; safe to overwrite (phase-2 sync already passed)
        #pragma unroll
        for (int r = 0; r < 16; ++r) {
            const int idx = r * 32 + l;
            const int h  = idx >> 8;
            const int n  = (idx >> 5) & 7;
            const int dd = idx & 31;
            sq[t][qidx(n, h, dd)] = o[r];
        }
    }
    __syncthreads();

    // ---------------- Phase 4: final block-diagonal projection ----------------
    // 256 threads = 128 output cols x 2 token-halves; each thread: 4 tokens.
    {
        const int c  = tid & 127;
        const int tg = tid >> 7;
        for (int n = 0; n < NB; ++n) {
            const float* wfp = wf + n * (EMB * BDIN) + c;
            float acc[4] = {0.f, 0.f, 0.f, 0.f};
            #pragma unroll
            for (int e = 0; e < EMB; ++e) {
                const float wv_ = wfp[(size_t)e * BDIN];   // 256B coalesced / wave
                const int   ai  = qidx(n, e >> 5, e & 31); // broadcast LDS read
                #pragma unroll
                for (int tt = 0; tt < 4; ++tt)
                    acc[tt] = fmaf(sq[tg * 4 + tt][ai], wv_, acc[tt]);
            }
            #pragma unroll
            for (int tt = 0; tt < 4; ++tt)
                out[(tok0 + tg * 4 + tt) * DIM + n * BDIN + c] = acc[tt];
        }
    }
}

extern "C" void kernel_launch(void* const* d_in, const int* in_sizes, int n_in,
                              void* d_out, int out_size, void* d_ws, size_t ws_size,
                              hipStream_t stream) {
    const float* x  = (const float*)d_in[0];
    const float* wq = (const float*)d_in[1];
    const float* wk = (const float*)d_in[2];
    const float* wv = (const float*)d_in[3];
    const float* wf = (const float*)d_in[4];
    float* out = (float*)d_out;

    const int tokens = in_sizes[0] / DIM;   // 32768
    const int grid   = tokens / T;          // 4096
    gc_fused<<<grid, 256, 0, stream>>>(x, wq, wk, wv, wf, out);
}

// Round 2
// 171.547 us; speedup vs baseline: 4.4091x; 4.4091x over previous
//
#include <hip/hip_runtime.h>
#include <math.h>

using short8 = __attribute__((ext_vector_type(8))) short;
using f32x4  = __attribute__((ext_vector_type(4))) float;

constexpr int DIM = 1024, NB = 8, BDIN = 128, EMB = 64, NH = 2, HD = 32;
constexpr int T   = 16;                  // tokens per workgroup
constexpr float SCALE = 0.17677669529663687f;  // HD^-0.5, folded into wq
constexpr int SXP = 136;                 // x-tile row stride (bf16): 272B -> 4-bank row step
constexpr int SQP = 1544;                // qkv row stride (bf16): 3088B -> 4-bank row step

__device__ __forceinline__ unsigned short f2bf(float f) {
  unsigned u = __float_as_uint(f);
  u += 0x7fff + ((u >> 16) & 1);         // RNE
  return (unsigned short)(u >> 16);
}
__device__ __forceinline__ float bf2f(unsigned short h) {
  return __uint_as_float((unsigned)h << 16);
}

// ---- prep: weights -> bf16, transposed for MFMA A-operand reads ----
// ws layout (ushort): wqT/wkT/wvT [8][e 64][k 128] at 0,64K,128K elems (wq pre-scaled);
//                     wfT [8][eo 128][k 64] at 192K elems. Total 512 KB.
__global__ __launch_bounds__(256) void prep_weights(
    const float* __restrict__ wq, const float* __restrict__ wk,
    const float* __restrict__ wv, const float* __restrict__ wf,
    unsigned short* __restrict__ ws)
{
  int gid = blockIdx.x * 256 + threadIdx.x;    // 0..262143
  int m = gid >> 16, r = gid & 65535;
  if (m < 3) {
    const float* w = (m == 0) ? wq : (m == 1) ? wk : wv;
    int n = r >> 13, e = (r >> 7) & 63, k = r & 127;
    float v = w[n * 8192 + k * 64 + e];
    if (m == 0) v *= SCALE;
    ws[m * 65536 + n * 8192 + e * 128 + k] = f2bf(v);
  } else {
    int n = r >> 13, ko = (r >> 6) & 127, e = r & 63;
    ws[3 * 65536 + n * 8192 + ko * 64 + e] = f2bf(wf[n * 8192 + e * 128 + ko]);
  }
}

__global__ __launch_bounds__(256, 2) void gc_main(
    const float* __restrict__ x,
    const unsigned short* __restrict__ wsq,
    const unsigned short* __restrict__ wsk,
    const unsigned short* __restrict__ wsv,
    const unsigned short* __restrict__ wsf,
    float* __restrict__ out)
{
  __shared__ __align__(16) unsigned short sx[2][T][SXP];     // x chunk, double-buffered
  __shared__ __align__(16) unsigned short sqkv[T][SQP];      // q|k|v rows (q later = attn_out)
  __shared__ float spT[T][NH][NB][NB + 1];                   // P^T: [t][h][m][n], pad 9

  const int tid  = threadIdx.x;
  const int lane = tid & 63;
  const int w    = tid >> 6;
  const long tok0 = (long)blockIdx.x * T;

  // ---------------- Phase A: QKV via MFMA (D[e][tok] = W^T X^T) ----------------
  const int fr = lane & 15;      // MFMA row/col lane index
  const int fg = lane >> 4;      // MFMA k-group

  float4 px0, px1;               // staged x (issue-early / write-late)
  auto stage_load = [&](int n) {
    int i0 = tid, i1 = tid + 256;                      // 512 float4 per chunk
    px0 = *reinterpret_cast<const float4*>(x + (tok0 + (i0 >> 5)) * DIM + n * BDIN + ((i0 & 31) << 2));
    px1 = *reinterpret_cast<const float4*>(x + (tok0 + (i1 >> 5)) * DIM + n * BDIN + ((i1 & 31) << 2));
  };
  auto stage_write = [&](int buf) {
    int i0 = tid, i1 = tid + 256;
    ushort4 b0, b1;
    b0.x = f2bf(px0.x); b0.y = f2bf(px0.y); b0.z = f2bf(px0.z); b0.w = f2bf(px0.w);
    b1.x = f2bf(px1.x); b1.y = f2bf(px1.y); b1.z = f2bf(px1.z); b1.w = f2bf(px1.w);
    *reinterpret_cast<ushort4*>(&sx[buf][i0 >> 5][(i0 & 31) << 2]) = b0;
    *reinterpret_cast<ushort4*>(&sx[buf][i1 >> 5][(i1 & 31) << 2]) = b1;
  };

  stage_load(0);
  stage_write(0);
  int buf = 0;
  for (int n = 0; n < NB; ++n) {
    __syncthreads();                       // sx[buf] ready; prev MFMA done with sx[buf^1]
    if (n < 7) stage_load(n + 1);          // issue next chunk's global loads
    // B-frags (X^T) for 4 k-steps, shared across this wave's 3 tiles
    short8 bfr[4];
    #pragma unroll
    for (int s = 0; s < 4; ++s)
      bfr[s] = *reinterpret_cast<const short8*>(&sx[buf][fr][s * 32 + fg * 8]);
    #pragma unroll
    for (int i = 0; i < 3; ++i) {
      int tau = w * 3 + i;                 // 12 (matrix, etile) tiles over 4 waves
      int m   = tau >> 2;                  // 0=q 1=k 2=v
      int et  = tau & 3;
      const unsigned short* wp =
          (m == 0 ? wsq : m == 1 ? wsk : wsv) + n * 8192 + (et * 16 + fr) * 128 + fg * 8;
      f32x4 acc = {0.f, 0.f, 0.f, 0.f};
      #pragma unroll
      for (int s = 0; s < 4; ++s) {
        short8 af = *reinterpret_cast<const short8*>(wp + s * 32);
        acc = __builtin_amdgcn_mfma_f32_16x16x32_bf16(af, bfr[s], acc, 0, 0, 0);
      }
      // D: lane holds D[e = et*16 + fg*4 + rr][tok = fr] -> 4 consecutive e: one b64 write
      ushort4 d4;
      d4.x = f2bf(acc[0]); d4.y = f2bf(acc[1]); d4.z = f2bf(acc[2]); d4.w = f2bf(acc[3]);
      *reinterpret_cast<ushort4*>(&sqkv[fr][m * 512 + n * 64 + et * 16 + fg * 4]) = d4;
    }
    if (n < 7) stage_write(buf ^ 1);       // vmcnt wait lands after MFMA issue
    buf ^= 1;
  }
  __syncthreads();                         // sqkv complete

  // ---------------- Phase B: scores + softmax (fp32, per (t,h,n-row)) ----------------
  {
    const int t  = tid >> 4;
    const int h  = (tid >> 3) & 1;
    const int nq = tid & 7;
    const unsigned short* qrow = &sqkv[t][nq * 64 + h * 32];
    float q[HD];
    #pragma unroll
    for (int cc = 0; cc < 4; ++cc) {       // rotate start by nq: breaks 8-way bank conflict
      int c = (cc + nq) & 3;
      short8 qv = *reinterpret_cast<const short8*>(qrow + c * 8);
      #pragma unroll
      for (int j = 0; j < 8; ++j) q[c * 8 + j] = bf2f((unsigned short)qv[j]);
    }
    float sc[NB];
    #pragma unroll
    for (int m = 0; m < NB; ++m) {
      const unsigned short* krow = &sqkv[t][512 + m * 64 + h * 32];  // broadcast across nq
      float a = 0.f;
      #pragma unroll
      for (int c = 0; c < 4; ++c) {
        short8 kv = *reinterpret_cast<const short8*>(krow + c * 8);
        #pragma unroll
        for (int j = 0; j < 8; ++j) a = fmaf(q[c * 8 + j], bf2f((unsigned short)kv[j]), a);
      }
      sc[m] = a;
    }
    float mx = sc[0];
    #pragma unroll
    for (int m = 1; m < NB; ++m) mx = fmaxf(mx, sc[m]);
    float sum = 0.f;
    #pragma unroll
    for (int m = 0; m < NB; ++m) { sc[m] = __expf(sc[m] - mx); sum += sc[m]; }
    const float inv = 1.f / sum;
    #pragma unroll
    for (int m = 0; m < NB; ++m) spT[t][h][m][nq] = sc[m] * inv;
  }
  __syncthreads();                         // q region free; P visible

  // ---------------- Phase C: attn_out = P @ V -> overwrite q region (bf16) ----------------
  {
    const int t = tid >> 4;
    const int h = (tid >> 3) & 1;
    const int g = tid & 7;                 // dd group of 4
    float acc[NB][4] = {};
    #pragma unroll
    for (int m = 0; m < NB; ++m) {
      ushort4 vv = *reinterpret_cast<const ushort4*>(&sqkv[t][1024 + m * 64 + h * 32 + g * 4]);
      float v0 = bf2f(vv.x), v1 = bf2f(vv.y), v2 = bf2f(vv.z), v3 = bf2f(vv.w);
      const float* pr = spT[t][h][m];
      #pragma unroll
      for (int n = 0; n < NB; ++n) {
        float p = pr[n];
        acc[n][0] = fmaf(p, v0, acc[n][0]);
        acc[n][1] = fmaf(p, v1, acc[n][1]);
        acc[n][2] = fmaf(p, v2, acc[n][2]);
        acc[n][3] = fmaf(p, v3, acc[n][3]);
      }
    }
    #pragma unroll
    for (int n = 0; n < NB; ++n) {
      ushort4 b;
      b.x = f2bf(acc[n][0]); b.y = f2bf(acc[n][1]); b.z = f2bf(acc[n][2]); b.w = f2bf(acc[n][3]);
      *reinterpret_cast<ushort4*>(&sqkv[t][n * 64 + h * 32 + g * 4]) = b;
    }
  }
  __syncthreads();

  // ---------------- Phase D: out = attn_out @ wf via MFMA, store float4 ----------------
  {
    #pragma unroll
    for (int bi = 0; bi < 2; ++bi) {
      int n = w * 2 + bi;
      short8 bfr[2];                       // attn_out^T frags, shared across 8 etiles
      #pragma unroll
      for (int s = 0; s < 2; ++s)
        bfr[s] = *reinterpret_cast<const short8*>(&sqkv[fr][n * 64 + s * 32 + fg * 8]);
      #pragma unroll
      for (int et = 0; et < 8; ++et) {
        const unsigned short* wp = wsf + n * 8192 + (et * 16 + fr) * 64 + fg * 8;
        f32x4 acc = {0.f, 0.f, 0.f, 0.f};
        #pragma unroll
        for (int s = 0; s < 2; ++s) {
          short8 af = *reinterpret_cast<const short8*>(wp + s * 32);
          acc = __builtin_amdgcn_mfma_f32_16x16x32_bf16(af, bfr[s], acc, 0, 0, 0);
        }
        float4 o; o.x = acc[0]; o.y = acc[1]; o.z = acc[2]; o.w = acc[3];
        *reinterpret_cast<float4*>(out + (tok0 + fr) * DIM + n * BDIN + et * 16 + fg * 4) = o;
      }
    }
  }
}

extern "C" void kernel_launch(void* const* d_in, const int* in_sizes, int n_in,
                              void* d_out, int out_size, void* d_ws, size_t ws_size,
                              hipStream_t stream) {
  const float* x  = (const float*)d_in[0];
  const float* wq = (const float*)d_in[1];
  const float* wk = (const float*)d_in[2];
  const float* wv = (const float*)d_in[3];
  const float* wf = (const float*)d_in[4];
  float* out = (float*)d_out;
  unsigned short* ws = (unsigned short*)d_ws;

  prep_weights<<<dim3(1024), dim3(256), 0, stream>>>(wq, wk, wv, wf, ws);

  const int tokens = in_sizes[0] / DIM;    // 32768
  gc_main<<<dim3(tokens / T), dim3(256), 0, stream>>>(
      x, ws, ws + 65536, ws + 131072, ws + 196608, out);
}